// Round 10
// baseline (177.180 us; speedup 1.0000x reference)
//
#include <hip/hip_runtime.h>

typedef __attribute__((ext_vector_type(4))) int int4v;

constexpr int Mdim = 32768;   // 8*4096
constexpr int Kdim = 1024;
constexpr int Ndim = 1024;
constexpr float FEPS = 1e-8f;

// ---------------- ws layout (bytes) ----------------
// 0      : float scalars[8]  {gamma_w, gamma_b, scale, sg, qs, inv_scale}
// 1024   : float partials[256]   (|W| partial sums)
// 4096   : unsigned pmax[2048]   (per-block |x| max bits)
// 16384  : float bq[1024]
// 32768  : int8 wq (1 MB)  -- TILED: tile t=(nb*16+kt) is 1KB; byte l*16 of tile t
//                             holds W[nb*16 + (l&15)][kt*64 + (l>>4)*16 .. +15]
constexpr size_t WQ_OFF = 32768;
constexpr size_t WS_NEED = WQ_OFF + (size_t)Ndim * Kdim;

// ---------------- pass 1 (merged): |x| absmax partials + |W| sum partials ----
__global__ void k_pre(const uint4* __restrict__ xv, const float4* __restrict__ wv,
                      unsigned* __restrict__ pmax, float* __restrict__ partials) {
  const int tid = threadIdx.x;
  if (blockIdx.x < 2048) {
    int i0 = blockIdx.x * 256 + tid;
    const int stride = 2048 * 256;
    const int n4 = Mdim * Kdim / 4;
    unsigned m = 0u;
    for (int i = i0; i < n4; i += stride) {
      uint4 v = xv[i];
      m = max(m, v.x & 0x7fffffffu);
      m = max(m, v.y & 0x7fffffffu);
      m = max(m, v.z & 0x7fffffffu);
      m = max(m, v.w & 0x7fffffffu);
    }
    #pragma unroll
    for (int off = 32; off > 0; off >>= 1)
      m = max(m, (unsigned)__shfl_down((int)m, off, 64));
    __shared__ unsigned red[4];
    if ((tid & 63) == 0) red[tid >> 6] = m;
    __syncthreads();
    if (tid == 0)
      pmax[blockIdx.x] = max(max(red[0], red[1]), max(red[2], red[3]));
  } else {
    int wb = blockIdx.x - 2048;
    float s = 0.f;
    const int stride = 256 * 256;
    const int n4 = Ndim * Kdim / 4;
    for (int i = wb * 256 + tid; i < n4; i += stride) {
      float4 v = wv[i];
      s += fabsf(v.x) + fabsf(v.y) + fabsf(v.z) + fabsf(v.w);
    }
    __shared__ float red[256];
    red[tid] = s;
    __syncthreads();
    for (int h = 128; h > 0; h >>= 1) {
      if (tid < h) red[tid] += red[tid + h];
      __syncthreads();
    }
    if (tid == 0) partials[wb] = red[0];
  }
}

// ---------------- pass 2: scalars + bias quant + W quant (256 blocks) --------
__global__ void k_finalize2(const float* __restrict__ bias, const float* __restrict__ w,
                            const float* __restrict__ partials, const unsigned* __restrict__ pmax,
                            float* __restrict__ scalars, float* __restrict__ bq,
                            unsigned char* __restrict__ wq) {
  __shared__ float red[256];
  const int t = threadIdx.x;
  const int b = blockIdx.x;

  red[t] = partials[t];
  __syncthreads();
  for (int h = 128; h > 0; h >>= 1) {
    if (t < h) red[t] += red[t + h];
    __syncthreads();
  }
  const float gw = red[0] / (1024.0f * 1024.0f);
  __syncthreads();
  const float inv_g = gw + FEPS;

  {
    const int tile = b * 4 + (t >> 6);   // 0..1023
    const int nb = tile >> 4;
    const int kt = tile & 15;
    const int l = t & 63;
    const float4* src = (const float4*)(w + (size_t)(nb * 16 + (l >> 2)) * Kdim + kt * 64 + (l & 3) * 16);
    unsigned o[4];
    #pragma unroll
    for (int v = 0; v < 4; ++v) {
      float4 f = src[v];
      int a  = (int)rintf(fminf(fmaxf(f.x / inv_g, -1.f), 1.f));
      int bb = (int)rintf(fminf(fmaxf(f.y / inv_g, -1.f), 1.f));
      int cc = (int)rintf(fminf(fmaxf(f.z / inv_g, -1.f), 1.f));
      int dd = (int)rintf(fminf(fmaxf(f.w / inv_g, -1.f), 1.f));
      o[v] = (unsigned)(a & 0xff) | ((unsigned)(bb & 0xff) << 8) |
             ((unsigned)(cc & 0xff) << 16) | ((unsigned)(dd & 0xff) << 24);
    }
    uint4 pk; pk.x = o[0]; pk.y = o[1]; pk.z = o[2]; pk.w = o[3];
    const int lp = (l >> 2) | ((l & 3) << 4);   // fragment lane
    *(uint4*)(wq + (size_t)tile * 1024 + lp * 16) = pk;
  }

  if (b != 0) return;

  __shared__ unsigned redu[256];
  __shared__ float sh_gb;
  unsigned m = 0u;
  #pragma unroll
  for (int i = 0; i < 8; ++i) m = max(m, pmax[t + 256 * i]);
  redu[t] = m;
  float s = fabsf(bias[t]) + fabsf(bias[t + 256]) + fabsf(bias[t + 512]) + fabsf(bias[t + 768]);
  red[t] = s;
  __syncthreads();
  for (int h = 128; h > 0; h >>= 1) {
    if (t < h) {
      red[t] += red[t + h];
      redu[t] = max(redu[t], redu[t + h]);
    }
    __syncthreads();
  }
  if (t == 0) {
    float gb = red[0] / 1024.0f;
    float maxval = __uint_as_float(redu[0]);
    float v = maxval / 127.0f + FEPS;
    int e = (int)((__float_as_uint(v) >> 23) & 0xff) - 127;
    float scale = ldexpf(1.0f, e);
    scalars[0] = gw;
    scalars[1] = gb;
    scalars[2] = scale;
    scalars[3] = scale * gw;       // epilogue multiplier
    scalars[4] = 127.0f * scale;   // clip bound (exact)
    scalars[5] = ldexpf(1.0f, -e); // inv_scale (exact power of 2)
    sh_gb = gb;
  }
  __syncthreads();
  float gb = sh_gb;
  for (int i = t; i < 1024; i += 256) {
    float q = rintf(bias[i] / (gb + FEPS));
    q = fminf(fmaxf(q, -1.0f), 1.0f);
    bq[i] = q * gb;
  }
}

// ---------------- pass 3: fused quant + int8 MFMA GEMM ----------------------
// 1024 blocks x 256 threads (4 waves), 32 KB LDS, VGPR cap 128 -> 4 blocks/CU
// co-resident: phase-A quantization of one block overlaps phase-B MFMA of the
// other three (no intra-block pipelining needed).
// Phase A: quantize the block's 32x1024 fp32 x-panel into LDS (32 tiles,
// fragment layout), one __syncthreads.
// Phase B: NO barriers. Wave wv owns rows [0,32) x cols np*256 + wv*64
// (unique per wave -> no duplicated B reads in-block; 256 KB/block, 256 MB
// device ~ 8 us of L2). B loaded global->VGPR with depth-2 named-register
// prefetch (pb*/qb*, fully static indices); A via conflict-free ds_read_b128.
// acc[2][4] = 32 AGPR; total regs ~100 < 128 cap, no spill.
__launch_bounds__(256, 4)
__global__ void k_megagemm(const float* __restrict__ x, const unsigned char* __restrict__ wq,
                           const float* __restrict__ scalars, const float* __restrict__ bq,
                           float* __restrict__ out) {
  __shared__ __align__(16) unsigned char Alds[32768];   // 32 tiles x 1KB

  const int tid = threadIdx.x;
  const int lane = tid & 63;
  const int wv = tid >> 6;          // 0..3  (= column-wave index)
  const int mtile = blockIdx.x;     // 0..1023 (32-row panel)
  const float qs = scalars[4], inv = scalars[5];

  // ---- Phase A: quantize 8 tiles per wave into LDS ----
  #pragma unroll
  for (int i = 0; i < 8; ++i) {
    const int tile = wv * 8 + i;    // 0..31 = mb*16 + kt
    const int mb = tile >> 4;       // 0..1
    const int kt = tile & 15;
    const float4* src = (const float4*)(x + (size_t)(mtile * 32 + mb * 16 + (lane >> 2)) * Kdim
                                          + kt * 64 + (lane & 3) * 16);
    unsigned o[4];
    #pragma unroll
    for (int v = 0; v < 4; ++v) {
      float4 f = src[v];
      int a = (int)rintf(fminf(fmaxf(f.x, -qs), qs) * inv);
      int b = (int)rintf(fminf(fmaxf(f.y, -qs), qs) * inv);
      int c = (int)rintf(fminf(fmaxf(f.z, -qs), qs) * inv);
      int d = (int)rintf(fminf(fmaxf(f.w, -qs), qs) * inv);
      o[v] = (unsigned)(a & 0xff) | ((unsigned)(b & 0xff) << 8) |
             ((unsigned)(c & 0xff) << 16) | ((unsigned)(d & 0xff) << 24);
    }
    uint4 pk; pk.x = o[0]; pk.y = o[1]; pk.z = o[2]; pk.w = o[3];
    const int lp = (lane >> 2) | ((lane & 3) << 4);   // fragment lane
    *(uint4*)(Alds + (size_t)tile * 1024 + lp * 16) = pk;
  }
  __syncthreads();   // the only barrier; Alds read-only below

  // ---- Phase B: 32 rows x 64 cols per wave per np, no barriers ----
  const float sg = scalars[3];
  const unsigned char* A0 = Alds + lane * 16;            // tile (mb=0, kt) at kt*1024
  const unsigned char* A1 = Alds + 16 * 1024 + lane * 16;// tile (mb=1, kt)

#define LB(r0, r1, r2, r3, Bb, kt_) do {                         \
    r0 = *(const int4v*)((Bb) + (size_t)((0 * 16 + (kt_))) * 1024); \
    r1 = *(const int4v*)((Bb) + (size_t)((1 * 16 + (kt_))) * 1024); \
    r2 = *(const int4v*)((Bb) + (size_t)((2 * 16 + (kt_))) * 1024); \
    r3 = *(const int4v*)((Bb) + (size_t)((3 * 16 + (kt_))) * 1024); \
  } while (0)

#define MF8(A0v, A1v, B0, B1, B2, B3) do {                                         \
    acc[0][0] = __builtin_amdgcn_mfma_i32_16x16x64_i8(A0v, B0, acc[0][0], 0, 0, 0); \
    acc[0][1] = __builtin_amdgcn_mfma_i32_16x16x64_i8(A0v, B1, acc[0][1], 0, 0, 0); \
    acc[0][2] = __builtin_amdgcn_mfma_i32_16x16x64_i8(A0v, B2, acc[0][2], 0, 0, 0); \
    acc[0][3] = __builtin_amdgcn_mfma_i32_16x16x64_i8(A0v, B3, acc[0][3], 0, 0, 0); \
    acc[1][0] = __builtin_amdgcn_mfma_i32_16x16x64_i8(A1v, B0, acc[1][0], 0, 0, 0); \
    acc[1][1] = __builtin_amdgcn_mfma_i32_16x16x64_i8(A1v, B1, acc[1][1], 0, 0, 0); \
    acc[1][2] = __builtin_amdgcn_mfma_i32_16x16x64_i8(A1v, B2, acc[1][2], 0, 0, 0); \
    acc[1][3] = __builtin_amdgcn_mfma_i32_16x16x64_i8(A1v, B3, acc[1][3], 0, 0, 0); \
  } while (0)

  #pragma unroll 1
  for (int np = 0; np < 4; ++np) {
    int4v acc[2][4];
    #pragma unroll
    for (int i = 0; i < 2; ++i)
      #pragma unroll
      for (int j = 0; j < 4; ++j)
        acc[i][j] = (int4v){0, 0, 0, 0};

    // this wave's 4 N-blocks: nb = np*16 + wv*4 + j
    const unsigned char* Bb = wq + ((size_t)(np * 16 + wv * 4) * 16) * 1024 + lane * 16;

    int4v pb0, pb1, pb2, pb3, qb0, qb1, qb2, qb3;
    LB(pb0, pb1, pb2, pb3, Bb, 0);
    LB(qb0, qb1, qb2, qb3, Bb, 1);

    #pragma unroll
    for (int kt = 0; kt < 16; kt += 2) {
      int4v a0 = *(const int4v*)(A0 + (size_t)kt * 1024);
      int4v a1 = *(const int4v*)(A1 + (size_t)kt * 1024);
      MF8(a0, a1, pb0, pb1, pb2, pb3);
      if (kt + 2 < 16) LB(pb0, pb1, pb2, pb3, Bb, kt + 2);
      int4v a2 = *(const int4v*)(A0 + (size_t)(kt + 1) * 1024);
      int4v a3 = *(const int4v*)(A1 + (size_t)(kt + 1) * 1024);
      MF8(a2, a3, qb0, qb1, qb2, qb3);
      if (kt + 3 < 16) LB(qb0, qb1, qb2, qb3, Bb, kt + 3);
    }

    // epilogue for this 256-col group (stores overlap next np's loads)
    #pragma unroll
    for (int nj = 0; nj < 4; ++nj) {
      const int col = np * 256 + wv * 64 + nj * 16 + (lane & 15);
      const float bb = bq[col];
      #pragma unroll
      for (int mi = 0; mi < 2; ++mi) {
        const int rowb = mtile * 32 + mi * 16 + (lane >> 4) * 4;
        #pragma unroll
        for (int r = 0; r < 4; ++r)
          out[(size_t)(rowb + r) * Ndim + col] = (float)acc[mi][nj][r] * sg + bb;
      }
    }
  }
#undef LB
#undef MF8
}

extern "C" void kernel_launch(void* const* d_in, const int* in_sizes, int n_in,
                              void* d_out, int out_size, void* d_ws, size_t ws_size,
                              hipStream_t stream) {
  const float* x = (const float*)d_in[0];
  const float* weight = (const float*)d_in[1];
  const float* bias = (const float*)d_in[2];
  float* out = (float*)d_out;

  if (ws_size < WS_NEED) return;

  char* ws = (char*)d_ws;
  float* scalars = (float*)ws;
  float* partials = (float*)(ws + 1024);
  unsigned* pmax = (unsigned*)(ws + 4096);
  float* bq = (float*)(ws + 16384);
  unsigned char* wq = (unsigned char*)(ws + WQ_OFF);

  k_pre<<<2304, 256, 0, stream>>>((const uint4*)x, (const float4*)weight, pmax, partials);
  k_finalize2<<<256, 256, 0, stream>>>(bias, weight, partials, pmax, scalars, bq, wq);
  k_megagemm<<<1024, 256, 0, stream>>>(x, wq, scalars, bq, out);
}